// Round 8
// baseline (171.627 us; speedup 1.0000x reference)
//
#include <hip/hip_runtime.h>
#include <math.h>

// v8 — contract dtypes (reference: fp32 in, fp32 out), never-yet-executed
// boring LDS simulator. One block (256 threads) per circuit; 1024 fp32
// amplitudes in LDS. No __shfl, no __sincosf, no __popc, no macros, no
// register-indexed arrays. Fresh symbol names vs all prior rounds.
//
//   d_in[0] x : (128, 10) fp32
//   d_in[1] w : (64, 10, 2) fp32
//   d_out     : (64, 128) fp32 ; circuit id = f*128 + b

__global__ void qsim_anchor_v8(const float* gx, const float* gw, float* gout) {
    __shared__ float amp[1024];
    __shared__ float acc[256];

    const int tid = (int)threadIdx.x;
    const int circ = (int)blockIdx.x;
    const int f = circ >> 7;
    const int b = circ & 127;

    for (int i = tid; i < 1024; i += 256) amp[i] = 0.0f;
    __syncthreads();
    if (tid == 0) amp[0] = 1.0f;
    __syncthreads();

    for (int stage = 0; stage < 3; ++stage) {
        // ten RY gates; qubit q lives on bit p = 9-q
        for (int q = 0; q < 10; ++q) {
            float theta;
            if (stage == 0) theta = gx[b * 10 + q];
            else            theta = gw[(f * 10 + q) * 2 + (stage - 1)];
            const float h = 0.5f * theta;
            const float cv = cosf(h);
            const float sv = sinf(h);
            const int p = 9 - q;
            const int pb = 1 << p;
            for (int j = tid; j < 512; j += 256) {
                const int lo = ((j >> p) << (p + 1)) | (j & (pb - 1));
                const int hi = lo | pb;
                const float a0 = amp[lo];
                const float a1 = amp[hi];
                amp[lo] = cv * a0 - sv * a1;
                amp[hi] = sv * a0 + cv * a1;
            }
            __syncthreads();
        }
        // CNOT ladder (only after the two weight layers)
        if (stage >= 1) {
            for (int q = 0; q < 9; ++q) {
                const int cbit = 1 << (9 - q);
                const int tbit = 1 << (8 - q);
                for (int i = tid; i < 1024; i += 256) {
                    if ((i & cbit) != 0 && (i & tbit) == 0) {
                        const float u0 = amp[i];
                        const float u1 = amp[i | tbit];
                        amp[i] = u1;
                        amp[i | tbit] = u0;
                    }
                }
                __syncthreads();
            }
        }
    }

    // <sum_k Z_k> = sum_i amp[i]^2 * (10 - 2*bits(i)); popcount via bit loop
    float loc = 0.0f;
    for (int i = tid; i < 1024; i += 256) {
        int bits = 0;
        for (int k = 0; k < 10; ++k) bits += (i >> k) & 1;
        const float a = amp[i];
        loc += a * a * (float)(10 - 2 * bits);
    }
    acc[tid] = loc;
    __syncthreads();
    for (int s = 128; s > 0; s >>= 1) {
        if (tid < s) acc[tid] += acc[tid + s];
        __syncthreads();
    }
    if (tid == 0) gout[circ] = acc[0];
}

extern "C" void kernel_launch(void* const* d_in, const int* in_sizes, int n_in,
                              void* d_out, int out_size, void* d_ws, size_t ws_size,
                              hipStream_t stream) {
    const float* x = (const float*)d_in[0];   // (128, 10) fp32
    const float* w = (const float*)d_in[1];   // (64, 10, 2) fp32
    float* out = (float*)d_out;               // (64, 128) fp32

    hipLaunchKernelGGL(qsim_anchor_v8, dim3(8192), dim3(256), 0, stream,
                       x, w, out);
}

// Round 10
// 106.608 us; speedup vs baseline: 1.6099x; 1.6099x over previous
//
#include <hip/hip_runtime.h>
#include <math.h>

// v10 = R8 (proven PASS) + two VALU cuts, structure otherwise untouched.
//  (a) block-shared trig: threads 0..29 compute the 30 (cos,sin) pairs once
//      into LDS (R8 had every thread do all 60 libm calls: ~57% of VALU).
//  (b) CNOT-ladder fusion: the 9-CNOT ladder == Gray permutation
//      new[j] = old[j ^ (j>>1)]  (b_k' = b_k^...^b_9; inverse = Gray code).
//      18 LDS passes + 18 barriers -> 2 passes + 4 barriers.
// Dtypes (R8-proven): x (128,10) fp32, w (64,10,2) fp32, out (64,128) fp32.
// One block (256 threads) per circuit; circ = blockIdx.x = f*128 + b.

__global__ void qsim_v10(const float* gx, const float* gw, float* gout) {
    __shared__ float amp[1024];
    __shared__ float2 cs[30];
    __shared__ float red[256];

    const int tid = (int)threadIdx.x;
    const int circ = (int)blockIdx.x;
    const int f = circ >> 7;
    const int b = circ & 127;

    // --- trig table: gate g<10 encoding x[b,g]; 10..19 layer0 w; 20..29 layer1 w
    if (tid < 30) {
        float th;
        if (tid < 10)      th = gx[b * 10 + tid];
        else if (tid < 20) th = gw[(f * 10 + (tid - 10)) * 2 + 0];
        else               th = gw[(f * 10 + (tid - 20)) * 2 + 1];
        const float h = 0.5f * th;
        cs[tid] = make_float2(cosf(h), sinf(h));
    }

    for (int i = tid; i < 1024; i += 256) amp[i] = 0.0f;
    __syncthreads();
    if (tid == 0) amp[0] = 1.0f;
    __syncthreads();

    for (int stage = 0; stage < 3; ++stage) {
        const int gbase = stage * 10;
        // ten RYs; qubit q acts on bit p = 9-q (compile-time after unroll)
        #pragma unroll
        for (int q = 0; q < 10; ++q) {
            const int p = 9 - q;
            const int pb = 1 << p;
            const float2 t = cs[gbase + q];
            const float cv = t.x, sv = t.y;
            #pragma unroll
            for (int k = 0; k < 2; ++k) {
                const int j = tid + k * 256;
                const int lo = ((j >> p) << (p + 1)) | (j & (pb - 1));
                const int hi = lo | pb;
                const float a0 = amp[lo];
                const float a1 = amp[hi];
                amp[lo] = cv * a0 - sv * a1;
                amp[hi] = sv * a0 + cv * a1;
            }
            __syncthreads();
        }
        // fused CNOT ladder: new[j] = old[j ^ (j>>1)], register-staged in-place
        if (stage >= 1) {
            const int j0 = tid, j1 = tid + 256, j2 = tid + 512, j3 = tid + 768;
            const float r0 = amp[j0 ^ (j0 >> 1)];
            const float r1 = amp[j1 ^ (j1 >> 1)];
            const float r2 = amp[j2 ^ (j2 >> 1)];
            const float r3 = amp[j3 ^ (j3 >> 1)];
            __syncthreads();
            amp[j0] = r0; amp[j1] = r1; amp[j2] = r2; amp[j3] = r3;
            __syncthreads();
        }
    }

    // <sum_k Z_k> = sum_i amp[i]^2 * (10 - 2*popcount(i))
    float loc = 0.0f;
    for (int i = tid; i < 1024; i += 256) {
        int bits = 0;
        for (int k = 0; k < 10; ++k) bits += (i >> k) & 1;
        const float a = amp[i];
        loc += a * a * (float)(10 - 2 * bits);
    }
    red[tid] = loc;
    __syncthreads();
    for (int s = 128; s > 0; s >>= 1) {
        if (tid < s) red[tid] += red[tid + s];
        __syncthreads();
    }
    if (tid == 0) gout[circ] = red[0];
}

extern "C" void kernel_launch(void* const* d_in, const int* in_sizes, int n_in,
                              void* d_out, int out_size, void* d_ws, size_t ws_size,
                              hipStream_t stream) {
    const float* x = (const float*)d_in[0];   // (128, 10) fp32
    const float* w = (const float*)d_in[1];   // (64, 10, 2) fp32
    float* out = (float*)d_out;               // (64, 128) fp32

    hipLaunchKernelGGL(qsim_v10, dim3(8192), dim3(256), 0, stream, x, w, out);
}

// Round 11
// 79.538 us; speedup vs baseline: 2.1578x; 1.3403x over previous
//
#include <hip/hip_runtime.h>
#include <math.h>

// v11 = v10 (PASS, 60us rocprof, VALUBusy 37% -> barrier-bound) restructured:
//  (a) stage-0 encoding == product state: amp[i] = up[i>>5]*lo[i&31]
//      (RY(th)|0> = cos|0>+sin|1>, qubit q <-> bit 9-q). 10 passes -> 1.
//  (b) commuting-RY fusion: rounds on bits {9,8,7}, {6,5,4} (8 reg amps/thread)
//      and {3,2,1,0} (16 reg amps/thread, tid<64, float4 LDS). 10 -> 3 passes.
//  (c) CNOT ladders (Gray perm new[j]=old[j^(j>>1)], v10-proven) folded into
//      stage-2 round-A gather reads and final reduction weights. 0 passes.
// Barriers ~46 -> 12. LDS/circuit ~274 KB -> ~57 KB.
// Dtypes (R8/R10-proven): x (128,10) fp32, w (64,10,2) fp32, out (64,128) fp32.

__device__ __forceinline__ void g2(float& a0, float& a1, float c, float s) {
    const float t0 = a0, t1 = a1;
    a0 = c * t0 - s * t1;
    a1 = s * t0 + c * t1;
}
__device__ __forceinline__ int pfx10(int x) {  // prefix-xor = ladder index map
    x ^= x >> 1; x ^= x >> 2; x ^= x >> 4; x ^= x >> 8;
    return x;
}

__global__ __launch_bounds__(128) void qsim_v11(const float* gx, const float* gw,
                                                float* gout) {
    __shared__ __align__(16) float amp[1024];
    __shared__ float2 cs[30];
    __shared__ float up[32], lo[32];
    __shared__ float red[128];

    const int tid = (int)threadIdx.x;
    const int circ = (int)blockIdx.x;   // f*128 + b
    const int f = circ >> 7, b = circ & 127;

    // 30 (cos,sin) pairs: gates 0..9 encoding x[b,*], 10..19 layer0, 20..29 layer1
    if (tid < 30) {
        float th = (tid < 10) ? gx[b * 10 + tid]
                 : (tid < 20) ? gw[(f * 10 + (tid - 10)) * 2 + 0]
                              : gw[(f * 10 + (tid - 20)) * 2 + 1];
        const float h = 0.5f * th;
        cs[tid] = make_float2(cosf(h), sinf(h));
    }
    __syncthreads();

    // product-state half tables: up over bits 9..5 (qubits 0..4), lo bits 4..0 (q 5..9)
    if (tid < 64) {
        const int idx = tid & 31;
        const int qb = (tid < 32) ? 0 : 5;
        float p = 1.0f;
        #pragma unroll
        for (int k = 0; k < 5; ++k) {
            const float2 t = cs[qb + k];
            p *= ((idx >> (4 - k)) & 1) ? t.y : t.x;
        }
        if (tid < 32) up[idx] = p; else lo[idx] = p;
    }
    __syncthreads();

    // init: encoded product state (replaces stage 0 entirely)
    #pragma unroll
    for (int k = 0; k < 8; ++k) {
        const int i = tid + 128 * k;
        amp[i] = up[i >> 5] * lo[i & 31];
    }
    __syncthreads();

    #pragma unroll 1
    for (int st = 0; st < 2; ++st) {
        const int gb = 10 + st * 10;

        // ---- round A: bits 9,8,7. st=1 gathers through layer-0's Gray perm.
        {
            float a[8];
            #pragma unroll
            for (int m = 0; m < 8; ++m) {
                const int j = tid + 128 * m;
                const int src = st ? (j ^ (j >> 1)) : j;
                a[m] = amp[src];
            }
            const float2 t9 = cs[gb + 0], t8 = cs[gb + 1], t7 = cs[gb + 2];
            g2(a[0],a[4],t9.x,t9.y); g2(a[1],a[5],t9.x,t9.y);
            g2(a[2],a[6],t9.x,t9.y); g2(a[3],a[7],t9.x,t9.y);
            g2(a[0],a[2],t8.x,t8.y); g2(a[1],a[3],t8.x,t8.y);
            g2(a[4],a[6],t8.x,t8.y); g2(a[5],a[7],t8.x,t8.y);
            g2(a[0],a[1],t7.x,t7.y); g2(a[2],a[3],t7.x,t7.y);
            g2(a[4],a[5],t7.x,t7.y); g2(a[6],a[7],t7.x,t7.y);
            __syncthreads();             // gather round: all reads before any write
            #pragma unroll
            for (int m = 0; m < 8; ++m) amp[tid + 128 * m] = a[m];
            __syncthreads();
        }

        // ---- round B: bits 6,5,4 (own-slot, single barrier)
        {
            const int base = ((tid >> 4) << 7) | (tid & 15);
            float a[8];
            #pragma unroll
            for (int m = 0; m < 8; ++m) a[m] = amp[base + 16 * m];
            const float2 t6 = cs[gb + 3], t5 = cs[gb + 4], t4 = cs[gb + 5];
            g2(a[0],a[4],t6.x,t6.y); g2(a[1],a[5],t6.x,t6.y);
            g2(a[2],a[6],t6.x,t6.y); g2(a[3],a[7],t6.x,t6.y);
            g2(a[0],a[2],t5.x,t5.y); g2(a[1],a[3],t5.x,t5.y);
            g2(a[4],a[6],t5.x,t5.y); g2(a[5],a[7],t5.x,t5.y);
            g2(a[0],a[1],t4.x,t4.y); g2(a[2],a[3],t4.x,t4.y);
            g2(a[4],a[5],t4.x,t4.y); g2(a[6],a[7],t4.x,t4.y);
            #pragma unroll
            for (int m = 0; m < 8; ++m) amp[base + 16 * m] = a[m];
            __syncthreads();
        }

        // ---- round CD: bits 3,2,1,0 — tid<64, 16 contiguous amps, float4 LDS
        if (st == 0) {
            if (tid < 64) {
                float4* av = (float4*)amp;
                float4 q0 = av[tid*4+0], q1 = av[tid*4+1], q2 = av[tid*4+2], q3 = av[tid*4+3];
                float a[16] = {q0.x,q0.y,q0.z,q0.w, q1.x,q1.y,q1.z,q1.w,
                               q2.x,q2.y,q2.z,q2.w, q3.x,q3.y,q3.z,q3.w};
                const float2 t3 = cs[gb+6], t2 = cs[gb+7], t1 = cs[gb+8], t0 = cs[gb+9];
                g2(a[0],a[8],t3.x,t3.y);  g2(a[1],a[9],t3.x,t3.y);
                g2(a[2],a[10],t3.x,t3.y); g2(a[3],a[11],t3.x,t3.y);
                g2(a[4],a[12],t3.x,t3.y); g2(a[5],a[13],t3.x,t3.y);
                g2(a[6],a[14],t3.x,t3.y); g2(a[7],a[15],t3.x,t3.y);
                g2(a[0],a[4],t2.x,t2.y);  g2(a[1],a[5],t2.x,t2.y);
                g2(a[2],a[6],t2.x,t2.y);  g2(a[3],a[7],t2.x,t2.y);
                g2(a[8],a[12],t2.x,t2.y); g2(a[9],a[13],t2.x,t2.y);
                g2(a[10],a[14],t2.x,t2.y);g2(a[11],a[15],t2.x,t2.y);
                g2(a[0],a[2],t1.x,t1.y);  g2(a[1],a[3],t1.x,t1.y);
                g2(a[4],a[6],t1.x,t1.y);  g2(a[5],a[7],t1.x,t1.y);
                g2(a[8],a[10],t1.x,t1.y); g2(a[9],a[11],t1.x,t1.y);
                g2(a[12],a[14],t1.x,t1.y);g2(a[13],a[15],t1.x,t1.y);
                g2(a[0],a[1],t0.x,t0.y);  g2(a[2],a[3],t0.x,t0.y);
                g2(a[4],a[5],t0.x,t0.y);  g2(a[6],a[7],t0.x,t0.y);
                g2(a[8],a[9],t0.x,t0.y);  g2(a[10],a[11],t0.x,t0.y);
                g2(a[12],a[13],t0.x,t0.y);g2(a[14],a[15],t0.x,t0.y);
                av[tid*4+0] = make_float4(a[0],a[1],a[2],a[3]);
                av[tid*4+1] = make_float4(a[4],a[5],a[6],a[7]);
                av[tid*4+2] = make_float4(a[8],a[9],a[10],a[11]);
                av[tid*4+3] = make_float4(a[12],a[13],a[14],a[15]);
            }
            __syncthreads();
        } else {
            // final round: gates + Z-weighted reduce through the last ladder
            float loc = 0.0f;
            if (tid < 64) {
                float4* av = (float4*)amp;
                float4 q0 = av[tid*4+0], q1 = av[tid*4+1], q2 = av[tid*4+2], q3 = av[tid*4+3];
                float a[16] = {q0.x,q0.y,q0.z,q0.w, q1.x,q1.y,q1.z,q1.w,
                               q2.x,q2.y,q2.z,q2.w, q3.x,q3.y,q3.z,q3.w};
                const float2 t3 = cs[gb+6], t2 = cs[gb+7], t1 = cs[gb+8], t0 = cs[gb+9];
                g2(a[0],a[8],t3.x,t3.y);  g2(a[1],a[9],t3.x,t3.y);
                g2(a[2],a[10],t3.x,t3.y); g2(a[3],a[11],t3.x,t3.y);
                g2(a[4],a[12],t3.x,t3.y); g2(a[5],a[13],t3.x,t3.y);
                g2(a[6],a[14],t3.x,t3.y); g2(a[7],a[15],t3.x,t3.y);
                g2(a[0],a[4],t2.x,t2.y);  g2(a[1],a[5],t2.x,t2.y);
                g2(a[2],a[6],t2.x,t2.y);  g2(a[3],a[7],t2.x,t2.y);
                g2(a[8],a[12],t2.x,t2.y); g2(a[9],a[13],t2.x,t2.y);
                g2(a[10],a[14],t2.x,t2.y);g2(a[11],a[15],t2.x,t2.y);
                g2(a[0],a[2],t1.x,t1.y);  g2(a[1],a[3],t1.x,t1.y);
                g2(a[4],a[6],t1.x,t1.y);  g2(a[5],a[7],t1.x,t1.y);
                g2(a[8],a[10],t1.x,t1.y); g2(a[9],a[11],t1.x,t1.y);
                g2(a[12],a[14],t1.x,t1.y);g2(a[13],a[15],t1.x,t1.y);
                g2(a[0],a[1],t0.x,t0.y);  g2(a[2],a[3],t0.x,t0.y);
                g2(a[4],a[5],t0.x,t0.y);  g2(a[6],a[7],t0.x,t0.y);
                g2(a[8],a[9],t0.x,t0.y);  g2(a[10],a[11],t0.x,t0.y);
                g2(a[12],a[13],t0.x,t0.y);g2(a[14],a[15],t0.x,t0.y);
                const int base = tid << 4;
                #pragma unroll
                for (int n = 0; n < 16; ++n) {
                    const int jf = pfx10(base + n);   // final ladder destination
                    int bits = 0;
                    #pragma unroll
                    for (int k = 0; k < 10; ++k) bits += (jf >> k) & 1;
                    loc += a[n] * a[n] * (float)(10 - 2 * bits);
                }
            }
            red[tid] = loc;
            __syncthreads();
            if (tid < 16) {
                red[tid] = red[tid] + red[tid + 16] + red[tid + 32] + red[tid + 48];
            }
            __syncthreads();
            if (tid == 0) {
                float s3 = 0.0f;
                #pragma unroll
                for (int k = 0; k < 16; ++k) s3 += red[k];
                gout[circ] = s3;
            }
        }
    }
}

extern "C" void kernel_launch(void* const* d_in, const int* in_sizes, int n_in,
                              void* d_out, int out_size, void* d_ws, size_t ws_size,
                              hipStream_t stream) {
    const float* x = (const float*)d_in[0];   // (128, 10) fp32
    const float* w = (const float*)d_in[1];   // (64, 10, 2) fp32
    float* out = (float*)d_out;               // (64, 128) fp32

    hipLaunchKernelGGL(qsim_v11, dim3(8192), dim3(128), 0, stream, x, w, out);
}

// Round 12
// 70.450 us; speedup vs baseline: 2.4361x; 1.1290x over previous
//
#include <hip/hip_runtime.h>
#include <math.h>

// v12 = v11 (PASS, bench 79.5us; kernel ~35-40us) + RY-merge algebraic cut:
//   RY(x_q) then RY(w_q0) on the same qubit with only commuting other-qubit
//   RYs between => RY(x_q + w_q0). The whole first layer merges into the
//   product-state init: amp0[i] = up[i>>5]*lo[i&31] with merged angles.
//   Circuit: P(merged) -> Gray -> RY(w1) -> Gray -> measure.
//   Round A computes its inputs directly from up/lo through the Gray map
//   (no init pass); final Gray folded into reduce weights via pfx10 (proven).
// Rounds A/B/CD are v11's proven code verbatim (gb=10). Barriers 12 -> 6.
// Dtypes (proven): x (128,10) fp32, w (64,10,2) fp32, out (64,128) fp32.

__device__ __forceinline__ void g2(float& a0, float& a1, float c, float s) {
    const float t0 = a0, t1 = a1;
    a0 = c * t0 - s * t1;
    a1 = s * t0 + c * t1;
}
__device__ __forceinline__ int pfx10(int x) {  // prefix-xor = ladder index map
    x ^= x >> 1; x ^= x >> 2; x ^= x >> 4; x ^= x >> 8;
    return x;
}

__global__ __launch_bounds__(128) void qsim_v12(const float* gx, const float* gw,
                                                float* gout) {
    __shared__ __align__(16) float amp[1024];
    __shared__ float2 cs[20];
    __shared__ float up[32], lo[32];
    __shared__ float red[128];

    const int tid = (int)threadIdx.x;
    const int circ = (int)blockIdx.x;   // f*128 + b
    const int f = circ >> 7, b = circ & 127;

    // trig: gates 0..9 merged (x[b,q]+w[f,q,0]); gates 10..19 layer-1 w[f,q,1]
    if (tid < 20) {
        float th;
        if (tid < 10) th = gx[b * 10 + tid] + gw[(f * 10 + tid) * 2 + 0];
        else          th = gw[(f * 10 + (tid - 10)) * 2 + 1];
        const float h = 0.5f * th;
        cs[tid] = make_float2(cosf(h), sinf(h));
    }
    __syncthreads();

    // product-state half tables over merged angles:
    // up: bits 9..5 (qubits 0..4), lo: bits 4..0 (qubits 5..9)
    if (tid < 64) {
        const int idx = tid & 31;
        const int qb = (tid < 32) ? 0 : 5;
        float p = 1.0f;
        #pragma unroll
        for (int k = 0; k < 5; ++k) {
            const float2 t = cs[qb + k];
            p *= ((idx >> (4 - k)) & 1) ? t.y : t.x;
        }
        if (tid < 32) up[idx] = p; else lo[idx] = p;
    }
    __syncthreads();

    // ---- round A: bits 9,8,7; inputs = product state gathered through the
    // layer-0 Gray permutation new[j] = old[j^(j>>1)] (v10/v11-proven map).
    {
        float a[8];
        #pragma unroll
        for (int m = 0; m < 8; ++m) {
            const int j = tid + 128 * m;
            const int src = j ^ (j >> 1);
            a[m] = up[src >> 5] * lo[src & 31];
        }
        const float2 t9 = cs[10], t8 = cs[11], t7 = cs[12];
        g2(a[0],a[4],t9.x,t9.y); g2(a[1],a[5],t9.x,t9.y);
        g2(a[2],a[6],t9.x,t9.y); g2(a[3],a[7],t9.x,t9.y);
        g2(a[0],a[2],t8.x,t8.y); g2(a[1],a[3],t8.x,t8.y);
        g2(a[4],a[6],t8.x,t8.y); g2(a[5],a[7],t8.x,t8.y);
        g2(a[0],a[1],t7.x,t7.y); g2(a[2],a[3],t7.x,t7.y);
        g2(a[4],a[5],t7.x,t7.y); g2(a[6],a[7],t7.x,t7.y);
        // reads were from up/lo (distinct arrays) -> no hazard with amp writes
        #pragma unroll
        for (int m = 0; m < 8; ++m) amp[tid + 128 * m] = a[m];
        __syncthreads();
    }

    // ---- round B: bits 6,5,4 (v11-verbatim)
    {
        const int base = ((tid >> 4) << 7) | (tid & 15);
        float a[8];
        #pragma unroll
        for (int m = 0; m < 8; ++m) a[m] = amp[base + 16 * m];
        const float2 t6 = cs[13], t5 = cs[14], t4 = cs[15];
        g2(a[0],a[4],t6.x,t6.y); g2(a[1],a[5],t6.x,t6.y);
        g2(a[2],a[6],t6.x,t6.y); g2(a[3],a[7],t6.x,t6.y);
        g2(a[0],a[2],t5.x,t5.y); g2(a[1],a[3],t5.x,t5.y);
        g2(a[4],a[6],t5.x,t5.y); g2(a[5],a[7],t5.x,t5.y);
        g2(a[0],a[1],t4.x,t4.y); g2(a[2],a[3],t4.x,t4.y);
        g2(a[4],a[5],t4.x,t4.y); g2(a[6],a[7],t4.x,t4.y);
        #pragma unroll
        for (int m = 0; m < 8; ++m) amp[base + 16 * m] = a[m];
        __syncthreads();
    }

    // ---- round CD: bits 3,2,1,0 + Z-reduce through the final Gray ladder
    float loc = 0.0f;
    if (tid < 64) {
        float4* av = (float4*)amp;
        float4 q0 = av[tid*4+0], q1 = av[tid*4+1], q2 = av[tid*4+2], q3 = av[tid*4+3];
        float a[16] = {q0.x,q0.y,q0.z,q0.w, q1.x,q1.y,q1.z,q1.w,
                       q2.x,q2.y,q2.z,q2.w, q3.x,q3.y,q3.z,q3.w};
        const float2 t3 = cs[16], t2 = cs[17], t1 = cs[18], t0 = cs[19];
        g2(a[0],a[8],t3.x,t3.y);  g2(a[1],a[9],t3.x,t3.y);
        g2(a[2],a[10],t3.x,t3.y); g2(a[3],a[11],t3.x,t3.y);
        g2(a[4],a[12],t3.x,t3.y); g2(a[5],a[13],t3.x,t3.y);
        g2(a[6],a[14],t3.x,t3.y); g2(a[7],a[15],t3.x,t3.y);
        g2(a[0],a[4],t2.x,t2.y);  g2(a[1],a[5],t2.x,t2.y);
        g2(a[2],a[6],t2.x,t2.y);  g2(a[3],a[7],t2.x,t2.y);
        g2(a[8],a[12],t2.x,t2.y); g2(a[9],a[13],t2.x,t2.y);
        g2(a[10],a[14],t2.x,t2.y);g2(a[11],a[15],t2.x,t2.y);
        g2(a[0],a[2],t1.x,t1.y);  g2(a[1],a[3],t1.x,t1.y);
        g2(a[4],a[6],t1.x,t1.y);  g2(a[5],a[7],t1.x,t1.y);
        g2(a[8],a[10],t1.x,t1.y); g2(a[9],a[11],t1.x,t1.y);
        g2(a[12],a[14],t1.x,t1.y);g2(a[13],a[15],t1.x,t1.y);
        g2(a[0],a[1],t0.x,t0.y);  g2(a[2],a[3],t0.x,t0.y);
        g2(a[4],a[5],t0.x,t0.y);  g2(a[6],a[7],t0.x,t0.y);
        g2(a[8],a[9],t0.x,t0.y);  g2(a[10],a[11],t0.x,t0.y);
        g2(a[12],a[13],t0.x,t0.y);g2(a[14],a[15],t0.x,t0.y);
        const int base = tid << 4;
        #pragma unroll
        for (int n = 0; n < 16; ++n) {
            const int jf = pfx10(base + n);   // final ladder destination
            int bits = 0;
            #pragma unroll
            for (int k = 0; k < 10; ++k) bits += (jf >> k) & 1;
            loc += a[n] * a[n] * (float)(10 - 2 * bits);
        }
    }
    red[tid] = loc;
    __syncthreads();
    if (tid < 16) {
        red[tid] = red[tid] + red[tid + 16] + red[tid + 32] + red[tid + 48];
    }
    __syncthreads();
    if (tid == 0) {
        float s3 = 0.0f;
        #pragma unroll
        for (int k = 0; k < 16; ++k) s3 += red[k];
        gout[circ] = s3;
    }
}

extern "C" void kernel_launch(void* const* d_in, const int* in_sizes, int n_in,
                              void* d_out, int out_size, void* d_ws, size_t ws_size,
                              hipStream_t stream) {
    const float* x = (const float*)d_in[0];   // (128, 10) fp32
    const float* w = (const float*)d_in[1];   // (64, 10, 2) fp32
    float* out = (float*)d_out;               // (64, 128) fp32

    hipLaunchKernelGGL(qsim_v12, dim3(8192), dim3(128), 0, stream, x, w, out);
}

// Round 13
// 58.996 us; speedup vs baseline: 2.9091x; 1.1942x over previous
//
#include <hip/hip_runtime.h>
#include <math.h>

// v13 — closed-form evaluation. No statevector, no LDS, no barriers.
//
// psi = U2 * R(phi) * U1 * P(theta)|0>, where theta_q = x[b,q]+w[f,q,0]
// (RY-merge, v12-proven), U = CNOT ladders, phi_q = w[f,q,1].
// Heisenberg: U2+ Z_k U2 = Z0..Zk ; R+ Z_q R = c_q Z_q - s_q X_q ;
// U1+ Z_q U1 = Z0..Zq ; U1+ X_q U1 = X_q X_{q+1} (X_9 for q=9).
// => E = sum_k <p| prod_{q<=k} B_q |p>,  B_q = c_q Z0..Zq - s_q X_q X_{q+1},
// over product state p with <Z>_q = cos(theta_q), <X>_q = sin(theta_q).
// Each term evaluates by a 4-state transfer DP (state = (a_q, suffix-Z-parity)):
//   emit qubit-(j+1) factor f(a_j, a_{j+1}, m_{j+1}):
//     (1,1,m): m? z:1   (1,0,m): m? x:0   (0,1,m): m? 0:x   (0,0,m): m? 1:z
//   m_j = m_{j+1} + (1 - a_{j+1}) mod 2 ; close at qubit 0 with a_{-1}=0.
// DP verified vs brute-force statevector on n=2 (3 numeric sign cases) and
// symbolically for k=1,2 (all subset terms incl. XZ->0 kills).
// Dtypes (proven): x (128,10) fp32, w (64,10,2) fp32, out (64,128) fp32.

__global__ void qnn_closed_v13(const float* gx, const float* gw, float* gout) {
    const int circ = (int)blockIdx.x * 64 + (int)threadIdx.x;   // f*128 + b
    const int f = circ >> 7, b = circ & 127;

    float z[10], xv[10], cc[10], ss[10];
    #pragma unroll
    for (int q = 0; q < 10; ++q) {
        const float th = gx[b * 10 + q] + gw[(f * 10 + q) * 2 + 0]; // merged
        z[q]  = cosf(th);
        xv[q] = sinf(th);
        const float ph = gw[(f * 10 + q) * 2 + 1];                  // layer 1
        cc[q] = cosf(ph);
        ss[q] = sinf(ph);
    }

    float E = 0.0f;
    #pragma unroll
    for (int k = 0; k < 10; ++k) {
        // init at q=k: a_k=0 -> c_k ; a_k=1 -> -s_k * (boundary x_{k+1})
        float v00 = cc[k];
        float v10 = -ss[k] * ((k < 9) ? xv[k + 1] : 1.0f);
        float v01 = 0.0f, v11 = 0.0f;
        #pragma unroll
        for (int j = k - 1; j >= 0; --j) {
            const float zj = z[j + 1], xj = xv[j + 1];
            const float n00 =  cc[j] * (v01 + xj * v10);   // (0,1,1)->x? no: see table
            const float n01 =  cc[j] * (zj * v00);
            const float n10 = -ss[j] * (xj * v01 + v10);
            const float n11 = -ss[j] * (zj * v11);
            v00 = n00; v01 = n01; v10 = n10; v11 = n11;
        }
        // close: qubit 0 factor g(a0, m0): g(1,0)=x0, g(0,0)=z0, g(0,1)=1, g(1,1)=0
        E += v00 * z[0] + v01 + v10 * xv[0];
    }

    gout[circ] = E;
}

extern "C" void kernel_launch(void* const* d_in, const int* in_sizes, int n_in,
                              void* d_out, int out_size, void* d_ws, size_t ws_size,
                              hipStream_t stream) {
    const float* x = (const float*)d_in[0];   // (128, 10) fp32
    const float* w = (const float*)d_in[1];   // (64, 10, 2) fp32
    float* out = (float*)d_out;               // (64, 128) fp32

    // 8192 circuits, one thread each: 128 blocks x 64 threads
    hipLaunchKernelGGL(qnn_closed_v13, dim3(128), dim3(64), 0, stream, x, w, out);
}

// Round 14
// 56.932 us; speedup vs baseline: 3.0146x; 1.0362x over previous
//
#include <hip/hip_runtime.h>
#include <math.h>

// v14 = v13 (closed-form transfer-matrix DP, PASS @ 59.0us bench) with the
// trig halved: block = one feature f (128 threads = its batches); the 20
// w-angle (cos,sin) pairs are computed once into LDS; the merged angle
// theta_q = x+w0 uses the addition identity (2 FMAs) instead of libm.
// Per-thread libm calls: 40 -> 20. DP core is v13-verbatim.
// Dtypes (proven): x (128,10) fp32, w (64,10,2) fp32, out (64,128) fp32.

__global__ __launch_bounds__(128) void qnn_closed_v14(const float* gx,
                                                      const float* gw,
                                                      float* gout) {
    __shared__ float wc0[10], ws0[10], wc1[10], ws1[10];
    const int b = (int)threadIdx.x;   // batch 0..127
    const int f = (int)blockIdx.x;    // feature 0..63

    if (b < 20) {
        const int q = b % 10;
        const int l = b / 10;
        const float a = gw[(f * 10 + q) * 2 + l];
        if (l == 0) { wc0[q] = cosf(a); ws0[q] = sinf(a); }
        else        { wc1[q] = cosf(a); ws1[q] = sinf(a); }
    }
    __syncthreads();

    // product-state moments for merged theta_q = x[b,q] + w[f,q,0]:
    //   z[q] = cos(theta), xv[q] = sin(theta)  (angle addition, 2 FMA each)
    // layer-1 rotation trig: cc/ss from LDS.
    float z[10], xv[10], cc[10], ss[10];
    #pragma unroll
    for (int q = 0; q < 10; ++q) {
        const float xa = gx[b * 10 + q];
        const float cx = cosf(xa), sx = sinf(xa);
        z[q]  = cx * wc0[q] - sx * ws0[q];
        xv[q] = sx * wc0[q] + cx * ws0[q];
        cc[q] = wc1[q];
        ss[q] = ws1[q];
    }

    // E = sum_k <p| prod_{q<=k} [cc_q Z0..Zq - ss_q X_q X_{q+1}] |p>
    // 4-state transfer DP, v13-verbatim (verified vs statevector).
    float E = 0.0f;
    #pragma unroll
    for (int k = 0; k < 10; ++k) {
        float v00 = cc[k];
        float v10 = -ss[k] * ((k < 9) ? xv[k + 1] : 1.0f);
        float v01 = 0.0f, v11 = 0.0f;
        #pragma unroll
        for (int j = k - 1; j >= 0; --j) {
            const float zj = z[j + 1], xj = xv[j + 1];
            const float n00 =  cc[j] * (v01 + xj * v10);
            const float n01 =  cc[j] * (zj * v00);
            const float n10 = -ss[j] * (xj * v01 + v10);
            const float n11 = -ss[j] * (zj * v11);
            v00 = n00; v01 = n01; v10 = n10; v11 = n11;
        }
        E += v00 * z[0] + v01 + v10 * xv[0];
    }

    gout[f * 128 + b] = E;
}

extern "C" void kernel_launch(void* const* d_in, const int* in_sizes, int n_in,
                              void* d_out, int out_size, void* d_ws, size_t ws_size,
                              hipStream_t stream) {
    const float* x = (const float*)d_in[0];   // (128, 10) fp32
    const float* w = (const float*)d_in[1];   // (64, 10, 2) fp32
    float* out = (float*)d_out;               // (64, 128) fp32

    // one block per feature, one thread per batch
    hipLaunchKernelGGL(qnn_closed_v14, dim3(64), dim3(128), 0, stream, x, w, out);
}